// Round 13
// baseline (40.331 us; speedup 1.0000x reference)
//
#include <hip/hip_runtime.h>
#include <math.h>

#define NQ   4
#define DIM  16
#define NL   6
#define TPB  256

#define INV2PI 0.15915494309189535f

typedef float f4v __attribute__((ext_vector_type(4)));

// Hardware trig: v_sin_f32 / v_cos_f32 take input in revolutions.
__device__ inline float hsin(float rad) { return __builtin_amdgcn_sinf(rad * INV2PI); }
__device__ inline float hcos(float rad) { return __builtin_amdgcn_cosf(rad * INV2PI); }

__host__ __device__ constexpr int cnotp(int c, int t, int idx) {
    return ((idx >> (3 - c)) & 1) ? (idx ^ (1 << (3 - t))) : idx;
}

// ---------------------------------------------------------------------------
// Setup (one block, 384 threads): parallel U build via __shfl_xor (r10,
// validated), then ReM_q = Re(U^dag D_q U), then the 81x4 tensor C to ws:
//   out_q = sum_{a,b,c,d} C[a,b,c,d][q] * u0_a u1_b u2_c u3_d,
//   u_i = (1, cos x_i, sin x_i).
// ---------------------------------------------------------------------------
__global__ __launch_bounds__(384) void build_all(const float* __restrict__ w,
                                                 float* __restrict__ Cg) {
    __shared__ float Ulds[DIM * DIM * 2];   // [(row*16+col)*2 + {re,im}]
    __shared__ float ReMs[DIM * DIM * 4];   // [(k*16+j)*4 + q]
    const int t = threadIdx.x;

    if (t < 256) {
        const int lane = t & 63;
        const int row  = lane & 15;
        const int col  = t >> 4;
        float cr = (row == col) ? 1.0f : 0.0f;
        float ci = 0.0f;

        #pragma unroll
        for (int l = 0; l < NL; ++l) {
            #pragma unroll
            for (int i = 0; i < NQ; ++i) {
                const float phi = w[(l * NQ + i) * 3 + 0];
                const float th  = w[(l * NQ + i) * 3 + 1];
                const float om  = w[(l * NQ + i) * 3 + 2];
                const float ct = hcos(0.5f * th),         st = hsin(0.5f * th);
                const float cp = hcos(0.5f * (phi + om)), sp = hsin(0.5f * (phi + om));
                const float cm = hcos(0.5f * (phi - om)), sm = hsin(0.5f * (phi - om));
                const float g00r =  cp * ct, g00i = -sp * ct;
                const float g01r = -cm * st, g01i = -sm * st;
                const float g10r =  cm * st, g10i = -sm * st;
                const float g11r =  cp * ct, g11i =  sp * ct;

                const int stride = 1 << (3 - i);
                const float pcr = __shfl_xor(cr, stride);
                const float pci = __shfl_xor(ci, stride);
                const bool hi = (row & stride) != 0;
                const float a_r = hi ? pcr : cr,  a_i = hi ? pci : ci;
                const float b_r = hi ? cr  : pcr, b_i = hi ? ci  : pci;
                const float G0r = hi ? g10r : g00r, G0i = hi ? g10i : g00i;
                const float G1r = hi ? g11r : g01r, G1i = hi ? g11i : g01i;
                cr = G0r * a_r - G0i * a_i + G1r * b_r - G1i * b_i;
                ci = G0r * a_i + G0i * a_r + G1r * b_i + G1i * b_r;
            }
            const int r = l % 3 + 1;
            int src = row;
            src = cnotp(3, (3 + r) & 3, src);
            src = cnotp(2, (2 + r) & 3, src);
            src = cnotp(1, (1 + r) & 3, src);
            src = cnotp(0, (0 + r) & 3, src);
            const int srcLane = (lane & ~15) | src;
            cr = __shfl(cr, srcLane);
            ci = __shfl(ci, srcLane);
        }
        Ulds[(row * DIM + col) * 2 + 0] = cr;
        Ulds[(row * DIM + col) * 2 + 1] = ci;
    }
    __syncthreads();

    if (t < 256) {
        const int j = t & 15, k = t >> 4;
        float s[4] = {0.f, 0.f, 0.f, 0.f};
        #pragma unroll
        for (int m = 0; m < DIM; ++m) {
            const float rr = Ulds[(m * DIM + j) * 2 + 0] * Ulds[(m * DIM + k) * 2 + 0]
                           + Ulds[(m * DIM + j) * 2 + 1] * Ulds[(m * DIM + k) * 2 + 1];
            #pragma unroll
            for (int q = 0; q < 4; ++q)
                s[q] += ((m >> (3 - q)) & 1) ? -rr : rr;
        }
        #pragma unroll
        for (int q = 0; q < 4; ++q) ReMs[(k * DIM + j) * 4 + q] = s[q];
    }
    __syncthreads();

    if (t < 324) {
        const int q = t & 3;
        const int r = t >> 2;                 // 0..80
        int e[4];
        e[3] = r % 3; e[2] = (r / 3) % 3; e[1] = (r / 9) % 3; e[0] = r / 27;
        float sum = 0.f;
        #pragma unroll
        for (int o = 0; o < 16; ++o) {
            int j = 0, k = 0; float wgt = 1.f;
            #pragma unroll
            for (int i = 0; i < 4; ++i) {
                const int oi = (o >> i) & 1;
                int bj, bk; float wi;
                if (e[i] == 0)      { bj = oi; bk = oi;     wi = 0.5f; }
                else if (e[i] == 1) { bj = oi; bk = oi;     wi = oi ? -0.5f : 0.5f; }
                else                { bj = oi; bk = oi ^ 1; wi = 0.5f; }
                j |= bj << (3 - i); k |= bk << (3 - i); wgt *= wi;
            }
            sum += wgt * ReMs[(k * DIM + j) * 4 + q];
        }
        Cg[r * 4 + q] = sum;
    }
}

// ---------------------------------------------------------------------------
// Main kernel, round 13: INSTRUMENTED. r9-structure body (best known: ELEM=2,
// b-level unrolled, 27-load bursts) wrapped in an npass internal loop so the
// dispatch exceeds the ~41 us rocprof top-5 cutoff and we finally read
// VALUBusy / Occupancy / VGPR / FETCH for the real inner loop. Per-pass
// asm-volatile keepalive with "memory" clobber (rule 17) prevents DCE of
// passes 0..npass-2 and load hoisting. Stores stay outside the loop (WRITE
// ~16 MB). Result = last pass, bit-identical to npass=1 -> still correct.
// ---------------------------------------------------------------------------
__global__ __launch_bounds__(TPB) void qsim(const f4v* __restrict__ x,
                                            const float* __restrict__ Cg,
                                            f4v* __restrict__ out, int T,
                                            int npass) {
    const int tid = blockIdx.x * TPB + threadIdx.x;
    if (tid >= T) return;

    float axA = 0.f, ayA = 0.f, azA = 0.f, awA = 0.f;
    float axB = 0.f, ayB = 0.f, azB = 0.f, awB = 0.f;
    const f4v* Cg4 = (const f4v*)Cg;

    #pragma unroll 1
    for (int p = 0; p < npass; ++p) {
        const f4v xa = x[tid];
        const f4v xb = x[tid + T];
        const float ca0 = hcos(xa.x), sa0 = hsin(xa.x);
        const float ca1 = hcos(xa.y), sa1 = hsin(xa.y);
        const float ca2 = hcos(xa.z), sa2 = hsin(xa.z);
        const float ca3 = hcos(xa.w), sa3 = hsin(xa.w);
        const float cb0 = hcos(xb.x), sb0 = hsin(xb.x);
        const float cb1 = hcos(xb.y), sb1 = hsin(xb.y);
        const float cb2 = hcos(xb.z), sb2 = hsin(xb.z);
        const float cb3 = hcos(xb.w), sb3 = hsin(xb.w);

        // basis over qubits 2,3: m=1..8 (m=0 is the constant-1 term)
        const float A1 = ca3, A2 = sa3, A3 = ca2, A4 = ca2 * ca3;
        const float A5 = ca2 * sa3, A6 = sa2, A7 = sa2 * ca3, A8 = sa2 * sa3;
        const float B1 = cb3, B2 = sb3, B3 = cb2, B4 = cb2 * cb3;
        const float B5 = cb2 * sb3, B6 = sb2, B7 = sb2 * cb3, B8 = sb2 * sb3;

        axA = 0.f; ayA = 0.f; azA = 0.f; awA = 0.f;
        axB = 0.f; ayB = 0.f; azB = 0.f; awB = 0.f;

        #pragma unroll 1
        for (int a = 0; a < 3; ++a) {
            f4v L[27];
            #pragma unroll
            for (int m = 0; m < 27; ++m) L[m] = Cg4[a * 27 + m];

            const float waA = (a == 0) ? 1.f : ((a == 1) ? ca0 : sa0);
            const float waB = (a == 0) ? 1.f : ((a == 1) ? cb0 : sb0);

            #pragma unroll
            for (int b = 0; b < 3; ++b) {
                const float wA = waA * ((b == 0) ? 1.f : ((b == 1) ? ca1 : sa1));
                const float wB = waB * ((b == 0) ? 1.f : ((b == 1) ? cb1 : sb1));

                float tx, ty, tz, tw;
                tx = L[b*9+0].x; ty = L[b*9+0].y; tz = L[b*9+0].z; tw = L[b*9+0].w;
                tx = fmaf(L[b*9+1].x, A1, tx); ty = fmaf(L[b*9+1].y, A1, ty);
                tz = fmaf(L[b*9+1].z, A1, tz); tw = fmaf(L[b*9+1].w, A1, tw);
                tx = fmaf(L[b*9+2].x, A2, tx); ty = fmaf(L[b*9+2].y, A2, ty);
                tz = fmaf(L[b*9+2].z, A2, tz); tw = fmaf(L[b*9+2].w, A2, tw);
                tx = fmaf(L[b*9+3].x, A3, tx); ty = fmaf(L[b*9+3].y, A3, ty);
                tz = fmaf(L[b*9+3].z, A3, tz); tw = fmaf(L[b*9+3].w, A3, tw);
                tx = fmaf(L[b*9+4].x, A4, tx); ty = fmaf(L[b*9+4].y, A4, ty);
                tz = fmaf(L[b*9+4].z, A4, tz); tw = fmaf(L[b*9+4].w, A4, tw);
                tx = fmaf(L[b*9+5].x, A5, tx); ty = fmaf(L[b*9+5].y, A5, ty);
                tz = fmaf(L[b*9+5].z, A5, tz); tw = fmaf(L[b*9+5].w, A5, tw);
                tx = fmaf(L[b*9+6].x, A6, tx); ty = fmaf(L[b*9+6].y, A6, ty);
                tz = fmaf(L[b*9+6].z, A6, tz); tw = fmaf(L[b*9+6].w, A6, tw);
                tx = fmaf(L[b*9+7].x, A7, tx); ty = fmaf(L[b*9+7].y, A7, ty);
                tz = fmaf(L[b*9+7].z, A7, tz); tw = fmaf(L[b*9+7].w, A7, tw);
                tx = fmaf(L[b*9+8].x, A8, tx); ty = fmaf(L[b*9+8].y, A8, ty);
                tz = fmaf(L[b*9+8].z, A8, tz); tw = fmaf(L[b*9+8].w, A8, tw);
                axA = fmaf(tx, wA, axA); ayA = fmaf(ty, wA, ayA);
                azA = fmaf(tz, wA, azA); awA = fmaf(tw, wA, awA);

                tx = L[b*9+0].x; ty = L[b*9+0].y; tz = L[b*9+0].z; tw = L[b*9+0].w;
                tx = fmaf(L[b*9+1].x, B1, tx); ty = fmaf(L[b*9+1].y, B1, ty);
                tz = fmaf(L[b*9+1].z, B1, tz); tw = fmaf(L[b*9+1].w, B1, tw);
                tx = fmaf(L[b*9+2].x, B2, tx); ty = fmaf(L[b*9+2].y, B2, ty);
                tz = fmaf(L[b*9+2].z, B2, tz); tw = fmaf(L[b*9+2].w, B2, tw);
                tx = fmaf(L[b*9+3].x, B3, tx); ty = fmaf(L[b*9+3].y, B3, ty);
                tz = fmaf(L[b*9+3].z, B3, tz); tw = fmaf(L[b*9+3].w, B3, tw);
                tx = fmaf(L[b*9+4].x, B4, tx); ty = fmaf(L[b*9+4].y, B4, ty);
                tz = fmaf(L[b*9+4].z, B4, tz); tw = fmaf(L[b*9+4].w, B4, tw);
                tx = fmaf(L[b*9+5].x, B5, tx); ty = fmaf(L[b*9+5].y, B5, ty);
                tz = fmaf(L[b*9+5].z, B5, tz); tw = fmaf(L[b*9+5].w, B5, tw);
                tx = fmaf(L[b*9+6].x, B6, tx); ty = fmaf(L[b*9+6].y, B6, ty);
                tz = fmaf(L[b*9+6].z, B6, tz); tw = fmaf(L[b*9+6].w, B6, tw);
                tx = fmaf(L[b*9+7].x, B7, tx); ty = fmaf(L[b*9+7].y, B7, ty);
                tz = fmaf(L[b*9+7].z, B7, tz); tw = fmaf(L[b*9+7].w, B7, tw);
                tx = fmaf(L[b*9+8].x, B8, tx); ty = fmaf(L[b*9+8].y, B8, ty);
                tz = fmaf(L[b*9+8].z, B8, tz); tw = fmaf(L[b*9+8].w, B8, tw);
                axB = fmaf(tx, wB, axB); ayB = fmaf(ty, wB, ayB);
                azB = fmaf(tz, wB, azB); awB = fmaf(tw, wB, awB);
            }
        }

        // Keep every pass live & ordered (rule 17): value-keep on all 8
        // accumulators + memory clobber so x/table loads are not hoisted.
        asm volatile("" : "+v"(axA), "+v"(ayA), "+v"(azA), "+v"(awA),
                          "+v"(axB), "+v"(ayB), "+v"(azB), "+v"(awB) :: "memory");
    }

    f4v oA = {axA, ayA, azA, awA};
    f4v oB = {axB, ayB, azB, awB};
    out[tid] = oA;
    out[tid + T] = oB;
}

extern "C" void kernel_launch(void* const* d_in, const int* in_sizes, int n_in,
                              void* d_out, int out_size, void* d_ws, size_t ws_size,
                              hipStream_t stream) {
    const float* x = (const float*)d_in[0];   // (B, 4) f32
    const float* w = (const float*)d_in[1];   // (6, 4, 3) f32
    float* Cg = (float*)d_ws;                 // 81 * float4 = 1296 B
    const int B = in_sizes[0] / NQ;           // 1048576
    const int T = B / 2;                      // ELEM=2

    build_all<<<1, 384, 0, stream>>>(w, Cg);
    // npass=4: diagnostic multiplier to lift qsim above the rocprof top-5
    // cutoff (~41 us). Result is identical to npass=1.
    qsim<<<(T + TPB - 1) / TPB, TPB, 0, stream>>>((const f4v*)x, Cg,
                                                  (f4v*)d_out, T, 4);
}

// Round 14
// 25.124 us; speedup vs baseline: 1.6053x; 1.6053x over previous
//
#include <hip/hip_runtime.h>
#include <math.h>

#define NQ   4
#define DIM  16
#define NL   6
#define TPB  256

#define INV2PI 0.15915494309189535f

typedef float f4v __attribute__((ext_vector_type(4)));

// Hardware trig: v_sin_f32 / v_cos_f32 take input in revolutions.
__device__ inline float hsin(float rad) { return __builtin_amdgcn_sinf(rad * INV2PI); }
__device__ inline float hcos(float rad) { return __builtin_amdgcn_cosf(rad * INV2PI); }

__host__ __device__ constexpr int cnotp(int c, int t, int idx) {
    return ((idx >> (3 - c)) & 1) ? (idx ^ (1 << (3 - t))) : idx;
}

__device__ inline f4v vfma(f4v a, float s, f4v c) {
    f4v r;
    r.x = fmaf(a.x, s, c.x);
    r.y = fmaf(a.y, s, c.y);
    r.z = fmaf(a.z, s, c.z);
    r.w = fmaf(a.w, s, c.w);
    return r;
}

// ---------------------------------------------------------------------------
// Setup (one block, 384 threads): parallel U build via __shfl_xor (r10,
// validated), then ReM_q = Re(U^dag D_q U), then the 81x4 tensor C to ws:
//   out_q = sum_{a,b,c,d} C[a,b,c,d][q] * u0_a u1_b u2_c u3_d,
//   u_i = (1, cos x_i, sin x_i).
// ---------------------------------------------------------------------------
__global__ __launch_bounds__(384) void build_all(const float* __restrict__ w,
                                                 float* __restrict__ Cg) {
    __shared__ float Ulds[DIM * DIM * 2];   // [(row*16+col)*2 + {re,im}]
    __shared__ float ReMs[DIM * DIM * 4];   // [(k*16+j)*4 + q]
    const int t = threadIdx.x;

    if (t < 256) {
        const int lane = t & 63;
        const int row  = lane & 15;
        const int col  = t >> 4;
        float cr = (row == col) ? 1.0f : 0.0f;
        float ci = 0.0f;

        #pragma unroll
        for (int l = 0; l < NL; ++l) {
            #pragma unroll
            for (int i = 0; i < NQ; ++i) {
                const float phi = w[(l * NQ + i) * 3 + 0];
                const float th  = w[(l * NQ + i) * 3 + 1];
                const float om  = w[(l * NQ + i) * 3 + 2];
                const float ct = hcos(0.5f * th),         st = hsin(0.5f * th);
                const float cp = hcos(0.5f * (phi + om)), sp = hsin(0.5f * (phi + om));
                const float cm = hcos(0.5f * (phi - om)), sm = hsin(0.5f * (phi - om));
                const float g00r =  cp * ct, g00i = -sp * ct;
                const float g01r = -cm * st, g01i = -sm * st;
                const float g10r =  cm * st, g10i = -sm * st;
                const float g11r =  cp * ct, g11i =  sp * ct;

                const int stride = 1 << (3 - i);
                const float pcr = __shfl_xor(cr, stride);
                const float pci = __shfl_xor(ci, stride);
                const bool hi = (row & stride) != 0;
                const float a_r = hi ? pcr : cr,  a_i = hi ? pci : ci;
                const float b_r = hi ? cr  : pcr, b_i = hi ? ci  : pci;
                const float G0r = hi ? g10r : g00r, G0i = hi ? g10i : g00i;
                const float G1r = hi ? g11r : g01r, G1i = hi ? g11i : g01i;
                cr = G0r * a_r - G0i * a_i + G1r * b_r - G1i * b_i;
                ci = G0r * a_i + G0i * a_r + G1r * b_i + G1i * b_r;
            }
            const int r = l % 3 + 1;
            int src = row;
            src = cnotp(3, (3 + r) & 3, src);
            src = cnotp(2, (2 + r) & 3, src);
            src = cnotp(1, (1 + r) & 3, src);
            src = cnotp(0, (0 + r) & 3, src);
            const int srcLane = (lane & ~15) | src;
            cr = __shfl(cr, srcLane);
            ci = __shfl(ci, srcLane);
        }
        Ulds[(row * DIM + col) * 2 + 0] = cr;
        Ulds[(row * DIM + col) * 2 + 1] = ci;
    }
    __syncthreads();

    if (t < 256) {
        const int j = t & 15, k = t >> 4;
        float s[4] = {0.f, 0.f, 0.f, 0.f};
        #pragma unroll
        for (int m = 0; m < DIM; ++m) {
            const float rr = Ulds[(m * DIM + j) * 2 + 0] * Ulds[(m * DIM + k) * 2 + 0]
                           + Ulds[(m * DIM + j) * 2 + 1] * Ulds[(m * DIM + k) * 2 + 1];
            #pragma unroll
            for (int q = 0; q < 4; ++q)
                s[q] += ((m >> (3 - q)) & 1) ? -rr : rr;
        }
        #pragma unroll
        for (int q = 0; q < 4; ++q) ReMs[(k * DIM + j) * 4 + q] = s[q];
    }
    __syncthreads();

    if (t < 324) {
        const int q = t & 3;
        const int r = t >> 2;                 // 0..80
        int e[4];
        e[3] = r % 3; e[2] = (r / 3) % 3; e[1] = (r / 9) % 3; e[0] = r / 27;
        float sum = 0.f;
        #pragma unroll
        for (int o = 0; o < 16; ++o) {
            int j = 0, k = 0; float wgt = 1.f;
            #pragma unroll
            for (int i = 0; i < 4; ++i) {
                const int oi = (o >> i) & 1;
                int bj, bk; float wi;
                if (e[i] == 0)      { bj = oi; bk = oi;     wi = 0.5f; }
                else if (e[i] == 1) { bj = oi; bk = oi;     wi = oi ? -0.5f : 0.5f; }
                else                { bj = oi; bk = oi ^ 1; wi = 0.5f; }
                j |= bj << (3 - i); k |= bk << (3 - i); wgt *= wi;
            }
            sum += wgt * ReMs[(k * DIM + j) * 4 + q];
        }
        Cg[r * 4 + q] = sum;
    }
}

// ---------------------------------------------------------------------------
// One ELEM=2 contraction (r12 body, validated; VALU-issue-bound per r13's
// marginal-pass measurement). L[9] per (a,b), both loops unroll-1 -> ~90
// VGPR live -> 4 waves/SIMD.
// ---------------------------------------------------------------------------
struct Pair { f4v a, b; };

__device__ inline Pair contract2(const f4v* __restrict__ Cg4, f4v xa, f4v xb) {
    const float ca0 = hcos(xa.x), sa0 = hsin(xa.x);
    const float ca1 = hcos(xa.y), sa1 = hsin(xa.y);
    const float ca2 = hcos(xa.z), sa2 = hsin(xa.z);
    const float ca3 = hcos(xa.w), sa3 = hsin(xa.w);
    const float cb0 = hcos(xb.x), sb0 = hsin(xb.x);
    const float cb1 = hcos(xb.y), sb1 = hsin(xb.y);
    const float cb2 = hcos(xb.z), sb2 = hsin(xb.z);
    const float cb3 = hcos(xb.w), sb3 = hsin(xb.w);

    const float A1 = ca3, A2 = sa3, A3 = ca2, A4 = ca2 * ca3;
    const float A5 = ca2 * sa3, A6 = sa2, A7 = sa2 * ca3, A8 = sa2 * sa3;
    const float B1 = cb3, B2 = sb3, B3 = cb2, B4 = cb2 * cb3;
    const float B5 = cb2 * sb3, B6 = sb2, B7 = sb2 * cb3, B8 = sb2 * sb3;

    f4v accA = {0.f, 0.f, 0.f, 0.f};
    f4v accB = {0.f, 0.f, 0.f, 0.f};

    #pragma unroll 1
    for (int a = 0; a < 3; ++a) {
        const float waA = (a == 0) ? 1.f : ((a == 1) ? ca0 : sa0);
        const float waB = (a == 0) ? 1.f : ((a == 1) ? cb0 : sb0);
        #pragma unroll 1
        for (int b = 0; b < 3; ++b) {
            const float wabA = waA * ((b == 0) ? 1.f : ((b == 1) ? ca1 : sa1));
            const float wabB = waB * ((b == 0) ? 1.f : ((b == 1) ? cb1 : sb1));

            f4v L[9];
            #pragma unroll
            for (int m = 0; m < 9; ++m) L[m] = Cg4[(a * 3 + b) * 9 + m];

            f4v TA = L[0];
            TA = vfma(L[1], A1, TA); TA = vfma(L[2], A2, TA);
            TA = vfma(L[3], A3, TA); TA = vfma(L[4], A4, TA);
            TA = vfma(L[5], A5, TA); TA = vfma(L[6], A6, TA);
            TA = vfma(L[7], A7, TA); TA = vfma(L[8], A8, TA);
            accA = vfma(TA, wabA, accA);

            f4v TB = L[0];
            TB = vfma(L[1], B1, TB); TB = vfma(L[2], B2, TB);
            TB = vfma(L[3], B3, TB); TB = vfma(L[4], B4, TB);
            TB = vfma(L[5], B5, TB); TB = vfma(L[6], B6, TB);
            TB = vfma(L[7], B7, TB); TB = vfma(L[8], B8, TB);
            accB = vfma(TB, wabB, accB);
        }
    }

    Pair r; r.a = accA; r.b = accB;
    return r;
}

// ---------------------------------------------------------------------------
// Main kernel, round 14. r13 npass-algebra: inner loop = 5.7 us (VALU-issue
// floor, model-exact); single-pass carries ~11.8 us FIXED — cold x fetch
// (d_ws poison fills evict L3 each replay), one-shot 16 MB store tail, and
// lockstep phases (all waves load/compute/store together -> phases ADD).
// Fix: two sequential ELEM=2 chunks per thread. All four x-loads issue up
// front (chunk-1 fetch hides under chunk-0's ~1700-cyc compute), chunk-0
// stores issue mid-kernel (overlap chunk-1 compute machine-wide), wave phase
// drift desynchronizes the memory bursts. Grid 1024 blocks, 4 waves/SIMD.
// ---------------------------------------------------------------------------
__global__ __launch_bounds__(TPB) void qsim(const f4v* __restrict__ x,
                                            const float* __restrict__ Cg,
                                            f4v* __restrict__ out,
                                            int NT, int T) {
    const int gid = blockIdx.x * TPB + threadIdx.x;
    const f4v* Cg4 = (const f4v*)Cg;

    // Issue all four input loads immediately (independent -> stay in flight).
    const f4v xa0 = x[gid];
    const f4v xb0 = x[gid + T];
    const f4v xa1 = x[gid + NT];
    const f4v xb1 = x[gid + NT + T];

    Pair r0 = contract2(Cg4, xa0, xb0);
    out[gid]     = r0.a;
    out[gid + T] = r0.b;

    Pair r1 = contract2(Cg4, xa1, xb1);
    out[gid + NT]     = r1.a;
    out[gid + NT + T] = r1.b;
}

extern "C" void kernel_launch(void* const* d_in, const int* in_sizes, int n_in,
                              void* d_out, int out_size, void* d_ws, size_t ws_size,
                              hipStream_t stream) {
    const float* x = (const float*)d_in[0];   // (B, 4) f32
    const float* w = (const float*)d_in[1];   // (6, 4, 3) f32
    float* Cg = (float*)d_ws;                 // 81 * float4 = 1296 B
    const int B = in_sizes[0] / NQ;           // 1048576
    const int T = B / 2;                      // pair stride
    const int NT = T / 2;                     // threads = 262144

    build_all<<<1, 384, 0, stream>>>(w, Cg);
    qsim<<<NT / TPB, TPB, 0, stream>>>((const f4v*)x, Cg, (f4v*)d_out, NT, T);
}

// Round 15
// 23.434 us; speedup vs baseline: 1.7210x; 1.0721x over previous
//
#include <hip/hip_runtime.h>
#include <math.h>

#define NQ   4
#define DIM  16
#define NL   6
#define TPB  256

#define INV2PI 0.15915494309189535f

typedef float f4v __attribute__((ext_vector_type(4)));

// Hardware trig: v_sin_f32 / v_cos_f32 take input in revolutions.
__device__ inline float hsin(float rad) { return __builtin_amdgcn_sinf(rad * INV2PI); }
__device__ inline float hcos(float rad) { return __builtin_amdgcn_cosf(rad * INV2PI); }

__host__ __device__ constexpr int cnotp(int c, int t, int idx) {
    return ((idx >> (3 - c)) & 1) ? (idx ^ (1 << (3 - t))) : idx;
}

__device__ inline f4v vfma(f4v a, float s, f4v c) {
    f4v r;
    r.x = fmaf(a.x, s, c.x);
    r.y = fmaf(a.y, s, c.y);
    r.z = fmaf(a.z, s, c.z);
    r.w = fmaf(a.w, s, c.w);
    return r;
}

// ---------------------------------------------------------------------------
// Setup (one block, 384 threads): parallel U build via __shfl_xor (r10,
// validated), then ReM_q = Re(U^dag D_q U), then the 81x4 tensor C to ws:
//   out_q = sum_{a,b,c,d} C[a,b,c,d][q] * u0_a u1_b u2_c u3_d,
//   u_i = (1, cos x_i, sin x_i).
// ---------------------------------------------------------------------------
__global__ __launch_bounds__(384) void build_all(const float* __restrict__ w,
                                                 float* __restrict__ Cg) {
    __shared__ float Ulds[DIM * DIM * 2];   // [(row*16+col)*2 + {re,im}]
    __shared__ float ReMs[DIM * DIM * 4];   // [(k*16+j)*4 + q]
    const int t = threadIdx.x;

    if (t < 256) {
        const int lane = t & 63;
        const int row  = lane & 15;
        const int col  = t >> 4;
        float cr = (row == col) ? 1.0f : 0.0f;
        float ci = 0.0f;

        #pragma unroll
        for (int l = 0; l < NL; ++l) {
            #pragma unroll
            for (int i = 0; i < NQ; ++i) {
                const float phi = w[(l * NQ + i) * 3 + 0];
                const float th  = w[(l * NQ + i) * 3 + 1];
                const float om  = w[(l * NQ + i) * 3 + 2];
                const float ct = hcos(0.5f * th),         st = hsin(0.5f * th);
                const float cp = hcos(0.5f * (phi + om)), sp = hsin(0.5f * (phi + om));
                const float cm = hcos(0.5f * (phi - om)), sm = hsin(0.5f * (phi - om));
                const float g00r =  cp * ct, g00i = -sp * ct;
                const float g01r = -cm * st, g01i = -sm * st;
                const float g10r =  cm * st, g10i = -sm * st;
                const float g11r =  cp * ct, g11i =  sp * ct;

                const int stride = 1 << (3 - i);
                const float pcr = __shfl_xor(cr, stride);
                const float pci = __shfl_xor(ci, stride);
                const bool hi = (row & stride) != 0;
                const float a_r = hi ? pcr : cr,  a_i = hi ? pci : ci;
                const float b_r = hi ? cr  : pcr, b_i = hi ? ci  : pci;
                const float G0r = hi ? g10r : g00r, G0i = hi ? g10i : g00i;
                const float G1r = hi ? g11r : g01r, G1i = hi ? g11i : g01i;
                cr = G0r * a_r - G0i * a_i + G1r * b_r - G1i * b_i;
                ci = G0r * a_i + G0i * a_r + G1r * b_i + G1i * b_r;
            }
            const int r = l % 3 + 1;
            int src = row;
            src = cnotp(3, (3 + r) & 3, src);
            src = cnotp(2, (2 + r) & 3, src);
            src = cnotp(1, (1 + r) & 3, src);
            src = cnotp(0, (0 + r) & 3, src);
            const int srcLane = (lane & ~15) | src;
            cr = __shfl(cr, srcLane);
            ci = __shfl(ci, srcLane);
        }
        Ulds[(row * DIM + col) * 2 + 0] = cr;
        Ulds[(row * DIM + col) * 2 + 1] = ci;
    }
    __syncthreads();

    if (t < 256) {
        const int j = t & 15, k = t >> 4;
        float s[4] = {0.f, 0.f, 0.f, 0.f};
        #pragma unroll
        for (int m = 0; m < DIM; ++m) {
            const float rr = Ulds[(m * DIM + j) * 2 + 0] * Ulds[(m * DIM + k) * 2 + 0]
                           + Ulds[(m * DIM + j) * 2 + 1] * Ulds[(m * DIM + k) * 2 + 1];
            #pragma unroll
            for (int q = 0; q < 4; ++q)
                s[q] += ((m >> (3 - q)) & 1) ? -rr : rr;
        }
        #pragma unroll
        for (int q = 0; q < 4; ++q) ReMs[(k * DIM + j) * 4 + q] = s[q];
    }
    __syncthreads();

    if (t < 324) {
        const int q = t & 3;
        const int r = t >> 2;                 // 0..80
        int e[4];
        e[3] = r % 3; e[2] = (r / 3) % 3; e[1] = (r / 9) % 3; e[0] = r / 27;
        float sum = 0.f;
        #pragma unroll
        for (int o = 0; o < 16; ++o) {
            int j = 0, k = 0; float wgt = 1.f;
            #pragma unroll
            for (int i = 0; i < 4; ++i) {
                const int oi = (o >> i) & 1;
                int bj, bk; float wi;
                if (e[i] == 0)      { bj = oi; bk = oi;     wi = 0.5f; }
                else if (e[i] == 1) { bj = oi; bk = oi;     wi = oi ? -0.5f : 0.5f; }
                else                { bj = oi; bk = oi ^ 1; wi = 0.5f; }
                j |= bj << (3 - i); k |= bk << (3 - i); wgt *= wi;
            }
            sum += wgt * ReMs[(k * DIM + j) * 4 + q];
        }
        Cg[r * 4 + q] = sum;
    }
}

// One 9-float4 table block -> the named register buffer Lb (static indices).
#define PREFETCH(Lb, blk) do { \
    Lb[0] = Cg4[(blk)*9+0]; Lb[1] = Cg4[(blk)*9+1]; Lb[2] = Cg4[(blk)*9+2]; \
    Lb[3] = Cg4[(blk)*9+3]; Lb[4] = Cg4[(blk)*9+4]; Lb[5] = Cg4[(blk)*9+5]; \
    Lb[6] = Cg4[(blk)*9+6]; Lb[7] = Cg4[(blk)*9+7]; Lb[8] = Cg4[(blk)*9+8]; \
} while (0)

// Contract one (a,b) block for both elements; weights WA/WB are registers.
#define COMPUTE(Lb, WA, WB) do { \
    f4v TA = Lb[0]; \
    TA = vfma(Lb[1], A1, TA); TA = vfma(Lb[2], A2, TA); \
    TA = vfma(Lb[3], A3, TA); TA = vfma(Lb[4], A4, TA); \
    TA = vfma(Lb[5], A5, TA); TA = vfma(Lb[6], A6, TA); \
    TA = vfma(Lb[7], A7, TA); TA = vfma(Lb[8], A8, TA); \
    accA = vfma(TA, (WA), accA); \
    f4v TB = Lb[0]; \
    TB = vfma(Lb[1], B1, TB); TB = vfma(Lb[2], B2, TB); \
    TB = vfma(Lb[3], B3, TB); TB = vfma(Lb[4], B4, TB); \
    TB = vfma(Lb[5], B5, TB); TB = vfma(Lb[6], B6, TB); \
    TB = vfma(Lb[7], B7, TB); TB = vfma(Lb[8], B8, TB); \
    accB = vfma(TB, (WB), accB); \
} while (0)

// ---------------------------------------------------------------------------
// Main kernel, round 15. r9-warm-launch (17.5us) vs r13-warm-pass (5.7us)
// localizes the 3x overhead INSIDE the wave: VALUBusy ~33% because each
// (a,b) iteration's table loads WAR-serialize against the previous block's
// FMAs (load->waitcnt->FMA->load chain, ~150-250cyc exposed per block).
// Fix: ping-pong register buffers LA/LB, fully unrolled 9-stage schedule —
// block i+1's loads are in flight during block i's ~190cyc FMA burst. Only
// 2 buffers exist, so the regalloc CANNOT hoist all 81 loads (r4 disaster
// is structurally excluded). ~120 VGPR -> 4 waves/SIMD.
// ---------------------------------------------------------------------------
__global__ __launch_bounds__(TPB) void qsim(const f4v* __restrict__ x,
                                            const float* __restrict__ Cg,
                                            f4v* __restrict__ out, int T) {
    const int tid = blockIdx.x * TPB + threadIdx.x;
    if (tid >= T) return;

    const f4v xa = x[tid];
    const f4v xb = x[tid + T];
    const float ca0 = hcos(xa.x), sa0 = hsin(xa.x);
    const float ca1 = hcos(xa.y), sa1 = hsin(xa.y);
    const float ca2 = hcos(xa.z), sa2 = hsin(xa.z);
    const float ca3 = hcos(xa.w), sa3 = hsin(xa.w);
    const float cb0 = hcos(xb.x), sb0 = hsin(xb.x);
    const float cb1 = hcos(xb.y), sb1 = hsin(xb.y);
    const float cb2 = hcos(xb.z), sb2 = hsin(xb.z);
    const float cb3 = hcos(xb.w), sb3 = hsin(xb.w);

    // Basis over qubits 2,3 (inner contraction operands).
    const float A1 = ca3, A2 = sa3, A3 = ca2, A4 = ca2 * ca3;
    const float A5 = ca2 * sa3, A6 = sa2, A7 = sa2 * ca3, A8 = sa2 * sa3;
    const float B1 = cb3, B2 = sb3, B3 = cb2, B4 = cb2 * cb3;
    const float B5 = cb2 * sb3, B6 = sb2, B7 = sb2 * cb3, B8 = sb2 * sb3;

    // Outer weights for the 9 (a,b) blocks (qubits 0,1).
    const float WA4 = ca0 * ca1, WA5 = ca0 * sa1, WA7 = sa0 * ca1, WA8 = sa0 * sa1;
    const float WB4 = cb0 * cb1, WB5 = cb0 * sb1, WB7 = sb0 * cb1, WB8 = sb0 * sb1;

    f4v accA = {0.f, 0.f, 0.f, 0.f};
    f4v accB = {0.f, 0.f, 0.f, 0.f};
    const f4v* Cg4 = (const f4v*)Cg;

    f4v LA[9], LB[9];
    PREFETCH(LA, 0);
    PREFETCH(LB, 1);
    COMPUTE(LA, 1.0f, 1.0f);   PREFETCH(LA, 2);   // (0,0)
    COMPUTE(LB, ca1,  cb1 );   PREFETCH(LB, 3);   // (0,1)
    COMPUTE(LA, sa1,  sb1 );   PREFETCH(LA, 4);   // (0,2)
    COMPUTE(LB, ca0,  cb0 );   PREFETCH(LB, 5);   // (1,0)
    COMPUTE(LA, WA4,  WB4 );   PREFETCH(LA, 6);   // (1,1)
    COMPUTE(LB, WA5,  WB5 );   PREFETCH(LB, 7);   // (1,2)
    COMPUTE(LA, sa0,  sb0 );   PREFETCH(LA, 8);   // (2,0)
    COMPUTE(LB, WA7,  WB7 );                      // (2,1)
    COMPUTE(LA, WA8,  WB8 );                      // (2,2)

    out[tid] = accA;
    out[tid + T] = accB;
}

extern "C" void kernel_launch(void* const* d_in, const int* in_sizes, int n_in,
                              void* d_out, int out_size, void* d_ws, size_t ws_size,
                              hipStream_t stream) {
    const float* x = (const float*)d_in[0];   // (B, 4) f32
    const float* w = (const float*)d_in[1];   // (6, 4, 3) f32
    float* Cg = (float*)d_ws;                 // 81 * float4 = 1296 B
    const int B = in_sizes[0] / NQ;           // 1048576
    const int T = B / 2;                      // ELEM=2

    build_all<<<1, 384, 0, stream>>>(w, Cg);
    qsim<<<(T + TPB - 1) / TPB, TPB, 0, stream>>>((const f4v*)x, Cg,
                                                  (f4v*)d_out, T);
}

// Round 16
// 22.460 us; speedup vs baseline: 1.7956x; 1.0434x over previous
//
#include <hip/hip_runtime.h>
#include <math.h>

#define NQ   4
#define DIM  16
#define NL   6
#define TPB  256

#define INV2PI 0.15915494309189535f

typedef float f4v __attribute__((ext_vector_type(4)));

// Hardware trig: v_sin_f32 / v_cos_f32 take input in revolutions.
__device__ inline float hsin(float rad) { return __builtin_amdgcn_sinf(rad * INV2PI); }
__device__ inline float hcos(float rad) { return __builtin_amdgcn_cosf(rad * INV2PI); }

__host__ __device__ constexpr int cnotp(int c, int t, int idx) {
    return ((idx >> (3 - c)) & 1) ? (idx ^ (1 << (3 - t))) : idx;
}

__device__ inline f4v vfma(f4v a, float s, f4v c) {
    f4v r;
    r.x = fmaf(a.x, s, c.x);
    r.y = fmaf(a.y, s, c.y);
    r.z = fmaf(a.z, s, c.z);
    r.w = fmaf(a.w, s, c.w);
    return r;
}

// ---------------------------------------------------------------------------
// Setup (one block, 384 threads): parallel U build via __shfl_xor (r10,
// validated), then ReM_q = Re(U^dag D_q U), then the 81x4 tensor C to ws:
//   out_q = sum_{a,b,c,d} C[a,b,c,d][q] * u0_a u1_b u2_c u3_d,
//   u_i = (1, cos x_i, sin x_i).
// ---------------------------------------------------------------------------
__global__ __launch_bounds__(384) void build_all(const float* __restrict__ w,
                                                 float* __restrict__ Cg) {
    __shared__ float Ulds[DIM * DIM * 2];   // [(row*16+col)*2 + {re,im}]
    __shared__ float ReMs[DIM * DIM * 4];   // [(k*16+j)*4 + q]
    const int t = threadIdx.x;

    if (t < 256) {
        const int lane = t & 63;
        const int row  = lane & 15;
        const int col  = t >> 4;
        float cr = (row == col) ? 1.0f : 0.0f;
        float ci = 0.0f;

        #pragma unroll
        for (int l = 0; l < NL; ++l) {
            #pragma unroll
            for (int i = 0; i < NQ; ++i) {
                const float phi = w[(l * NQ + i) * 3 + 0];
                const float th  = w[(l * NQ + i) * 3 + 1];
                const float om  = w[(l * NQ + i) * 3 + 2];
                const float ct = hcos(0.5f * th),         st = hsin(0.5f * th);
                const float cp = hcos(0.5f * (phi + om)), sp = hsin(0.5f * (phi + om));
                const float cm = hcos(0.5f * (phi - om)), sm = hsin(0.5f * (phi - om));
                const float g00r =  cp * ct, g00i = -sp * ct;
                const float g01r = -cm * st, g01i = -sm * st;
                const float g10r =  cm * st, g10i = -sm * st;
                const float g11r =  cp * ct, g11i =  sp * ct;

                const int stride = 1 << (3 - i);
                const float pcr = __shfl_xor(cr, stride);
                const float pci = __shfl_xor(ci, stride);
                const bool hi = (row & stride) != 0;
                const float a_r = hi ? pcr : cr,  a_i = hi ? pci : ci;
                const float b_r = hi ? cr  : pcr, b_i = hi ? ci  : pci;
                const float G0r = hi ? g10r : g00r, G0i = hi ? g10i : g00i;
                const float G1r = hi ? g11r : g01r, G1i = hi ? g11i : g01i;
                cr = G0r * a_r - G0i * a_i + G1r * b_r - G1i * b_i;
                ci = G0r * a_i + G0i * a_r + G1r * b_i + G1i * b_r;
            }
            const int r = l % 3 + 1;
            int src = row;
            src = cnotp(3, (3 + r) & 3, src);
            src = cnotp(2, (2 + r) & 3, src);
            src = cnotp(1, (1 + r) & 3, src);
            src = cnotp(0, (0 + r) & 3, src);
            const int srcLane = (lane & ~15) | src;
            cr = __shfl(cr, srcLane);
            ci = __shfl(ci, srcLane);
        }
        Ulds[(row * DIM + col) * 2 + 0] = cr;
        Ulds[(row * DIM + col) * 2 + 1] = ci;
    }
    __syncthreads();

    if (t < 256) {
        const int j = t & 15, k = t >> 4;
        float s[4] = {0.f, 0.f, 0.f, 0.f};
        #pragma unroll
        for (int m = 0; m < DIM; ++m) {
            const float rr = Ulds[(m * DIM + j) * 2 + 0] * Ulds[(m * DIM + k) * 2 + 0]
                           + Ulds[(m * DIM + j) * 2 + 1] * Ulds[(m * DIM + k) * 2 + 1];
            #pragma unroll
            for (int q = 0; q < 4; ++q)
                s[q] += ((m >> (3 - q)) & 1) ? -rr : rr;
        }
        #pragma unroll
        for (int q = 0; q < 4; ++q) ReMs[(k * DIM + j) * 4 + q] = s[q];
    }
    __syncthreads();

    if (t < 324) {
        const int q = t & 3;
        const int r = t >> 2;                 // 0..80
        int e[4];
        e[3] = r % 3; e[2] = (r / 3) % 3; e[1] = (r / 9) % 3; e[0] = r / 27;
        float sum = 0.f;
        #pragma unroll
        for (int o = 0; o < 16; ++o) {
            int j = 0, k = 0; float wgt = 1.f;
            #pragma unroll
            for (int i = 0; i < 4; ++i) {
                const int oi = (o >> i) & 1;
                int bj, bk; float wi;
                if (e[i] == 0)      { bj = oi; bk = oi;     wi = 0.5f; }
                else if (e[i] == 1) { bj = oi; bk = oi;     wi = oi ? -0.5f : 0.5f; }
                else                { bj = oi; bk = oi ^ 1; wi = 0.5f; }
                j |= bj << (3 - i); k |= bk << (3 - i); wgt *= wi;
            }
            sum += wgt * ReMs[(k * DIM + j) * 4 + q];
        }
        Cg[r * 4 + q] = sum;
    }
}

// ---------------------------------------------------------------------------
// Main kernel, round 16. Eight structural variants all pin at 23.4 us; the
// r13/r9 books say q = 5.7 compute (measured marginal) + ~5.1 HBM floor +
// ~5 cold-read/store-allocate residual. The one untried mechanism: x is
// read once and out written once per replay (L3 evicted by the 256 MB d_ws
// poison fill between replays) -> NON-TEMPORAL loads/stores. NT stores skip
// write-allocate on cold out lines; NT loads skip L2/L3 allocation for
// never-reused x. Body is the r12 contraction verbatim (proven equal-best).
// ---------------------------------------------------------------------------
__global__ __launch_bounds__(TPB) void qsim(const f4v* __restrict__ x,
                                            const float* __restrict__ Cg,
                                            f4v* __restrict__ out, int T) {
    const int tid = blockIdx.x * TPB + threadIdx.x;
    if (tid >= T) return;

    const f4v xa = __builtin_nontemporal_load(x + tid);
    const f4v xb = __builtin_nontemporal_load(x + tid + T);
    const float ca0 = hcos(xa.x), sa0 = hsin(xa.x);
    const float ca1 = hcos(xa.y), sa1 = hsin(xa.y);
    const float ca2 = hcos(xa.z), sa2 = hsin(xa.z);
    const float ca3 = hcos(xa.w), sa3 = hsin(xa.w);
    const float cb0 = hcos(xb.x), sb0 = hsin(xb.x);
    const float cb1 = hcos(xb.y), sb1 = hsin(xb.y);
    const float cb2 = hcos(xb.z), sb2 = hsin(xb.z);
    const float cb3 = hcos(xb.w), sb3 = hsin(xb.w);

    // basis products over qubits 2,3: m=1..8 (m=0 is the constant-1 term)
    const float A1 = ca3, A2 = sa3, A3 = ca2, A4 = ca2 * ca3;
    const float A5 = ca2 * sa3, A6 = sa2, A7 = sa2 * ca3, A8 = sa2 * sa3;
    const float B1 = cb3, B2 = sb3, B3 = cb2, B4 = cb2 * cb3;
    const float B5 = cb2 * sb3, B6 = sb2, B7 = sb2 * cb3, B8 = sb2 * sb3;

    f4v accA = {0.f, 0.f, 0.f, 0.f};
    f4v accB = {0.f, 0.f, 0.f, 0.f};
    const f4v* Cg4 = (const f4v*)Cg;

    #pragma unroll 1
    for (int a = 0; a < 3; ++a) {
        const float waA = (a == 0) ? 1.f : ((a == 1) ? ca0 : sa0);
        const float waB = (a == 0) ? 1.f : ((a == 1) ? cb0 : sb0);
        #pragma unroll 1
        for (int b = 0; b < 3; ++b) {
            const float wabA = waA * ((b == 0) ? 1.f : ((b == 1) ? ca1 : sa1));
            const float wabB = waB * ((b == 0) ? 1.f : ((b == 1) ? cb1 : sb1));

            f4v L[9];
            #pragma unroll
            for (int m = 0; m < 9; ++m) L[m] = Cg4[(a * 3 + b) * 9 + m];

            f4v TA = L[0];
            TA = vfma(L[1], A1, TA); TA = vfma(L[2], A2, TA);
            TA = vfma(L[3], A3, TA); TA = vfma(L[4], A4, TA);
            TA = vfma(L[5], A5, TA); TA = vfma(L[6], A6, TA);
            TA = vfma(L[7], A7, TA); TA = vfma(L[8], A8, TA);
            accA = vfma(TA, wabA, accA);

            f4v TB = L[0];
            TB = vfma(L[1], B1, TB); TB = vfma(L[2], B2, TB);
            TB = vfma(L[3], B3, TB); TB = vfma(L[4], B4, TB);
            TB = vfma(L[5], B5, TB); TB = vfma(L[6], B6, TB);
            TB = vfma(L[7], B7, TB); TB = vfma(L[8], B8, TB);
            accB = vfma(TB, wabB, accB);
        }
    }

    __builtin_nontemporal_store(accA, out + tid);
    __builtin_nontemporal_store(accB, out + tid + T);
}

extern "C" void kernel_launch(void* const* d_in, const int* in_sizes, int n_in,
                              void* d_out, int out_size, void* d_ws, size_t ws_size,
                              hipStream_t stream) {
    const float* x = (const float*)d_in[0];   // (B, 4) f32
    const float* w = (const float*)d_in[1];   // (6, 4, 3) f32
    float* Cg = (float*)d_ws;                 // 81 * float4 = 1296 B
    const int B = in_sizes[0] / NQ;           // 1048576
    const int T = B / 2;                      // ELEM=2

    build_all<<<1, 384, 0, stream>>>(w, Cg);
    qsim<<<(T + TPB - 1) / TPB, TPB, 0, stream>>>((const f4v*)x, Cg,
                                                  (f4v*)d_out, T);
}